// Round 9
// baseline (403.562 us; speedup 1.0000x reference)
//
#include <hip/hip_runtime.h>
#include <math.h>

typedef unsigned short u16;
typedef unsigned int u32;
typedef __attribute__((ext_vector_type(8))) short s16x8;
typedef __attribute__((ext_vector_type(4))) float f32x4;
typedef __attribute__((ext_vector_type(2))) float f32x2;

__device__ __forceinline__ float bf2f(u16 u) { return __uint_as_float(((u32)u) << 16); }
__device__ __forceinline__ u16 f2bf(float f) {
    u32 u = __float_as_uint(f);
    return (u16)((u + 0x7fffu + ((u >> 16) & 1u)) >> 16);  // RNE
}

union U4 { u32 u[4]; s16x8 v; };

__device__ __forceinline__ s16x8 pack_hi(f32x4 x0, f32x4 x1) {
    U4 r;
    r.u[0] = (__float_as_uint(x0.y) & 0xFFFF0000u) | (__float_as_uint(x0.x) >> 16);
    r.u[1] = (__float_as_uint(x0.w) & 0xFFFF0000u) | (__float_as_uint(x0.z) >> 16);
    r.u[2] = (__float_as_uint(x1.y) & 0xFFFF0000u) | (__float_as_uint(x1.x) >> 16);
    r.u[3] = (__float_as_uint(x1.w) & 0xFFFF0000u) | (__float_as_uint(x1.z) >> 16);
    return r.v;
}
__device__ __forceinline__ s16x8 pack_lo(f32x4 x0, f32x4 x1) {
    float e0 = x0.x - __uint_as_float(__float_as_uint(x0.x) & 0xFFFF0000u);
    float e1 = x0.y - __uint_as_float(__float_as_uint(x0.y) & 0xFFFF0000u);
    float e2 = x0.z - __uint_as_float(__float_as_uint(x0.z) & 0xFFFF0000u);
    float e3 = x0.w - __uint_as_float(__float_as_uint(x0.w) & 0xFFFF0000u);
    float e4 = x1.x - __uint_as_float(__float_as_uint(x1.x) & 0xFFFF0000u);
    float e5 = x1.y - __uint_as_float(__float_as_uint(x1.y) & 0xFFFF0000u);
    float e6 = x1.z - __uint_as_float(__float_as_uint(x1.z) & 0xFFFF0000u);
    float e7 = x1.w - __uint_as_float(__float_as_uint(x1.w) & 0xFFFF0000u);
    U4 r;
    r.u[0] = (__float_as_uint(e1) & 0xFFFF0000u) | (__float_as_uint(e0) >> 16);
    r.u[1] = (__float_as_uint(e3) & 0xFFFF0000u) | (__float_as_uint(e2) >> 16);
    r.u[2] = (__float_as_uint(e5) & 0xFFFF0000u) | (__float_as_uint(e4) >> 16);
    r.u[3] = (__float_as_uint(e7) & 0xFFFF0000u) | (__float_as_uint(e6) >> 16);
    return r.v;
}

#define BSHIFT 9
#define BSIZE 512
#define BCAP 10240  // entries per bin region; mean 8192, sigma ~90

struct PackArgs { const float* w[6]; };

// ---------------- weight pre-pack into MFMA B-fragment order (bf16 RNE) ----------------

__device__ __forceinline__ void pack_body(const PackArgs& pa, u16* __restrict__ out, int g, int t) {
    const int Ks[6] = {128, 128, 64, 64, 64, 128};
    const int Ms[6] = {128, 64, 64, 64, 128, 128};
    const int Off[6] = {0, 16384, 24576, 28672, 32768, 40960};
    int s = g >> 6;
    int id = (g & 63) * 256 + t;
    int K = Ks[s], M = Ms[s];
    if (id >= K * M) return;
    int ms = (M == 128) ? 7 : 6;
    int k = id >> ms, c = id & (M - 1);
    int chunk = k >> 5, j = k & 7, lq = (k >> 3) & 3;
    int ct = c >> 4, ln = (c & 15) + (lq << 4);
    out[Off[s] + (chunk * (M >> 4) + ct) * 512 + ln * 8 + j] = f2bf(pa.w[s][id]);
}

// ---------------- k1: bin edges by dst>>9 (blocks [0,C)) + weight pack (blocks [C,C+384)) ----------------

__global__ __launch_bounds__(256) void k_bin_pack(const int* __restrict__ ei, int E, int NB, int C,
                                                  int* __restrict__ bin_cursor, u32* __restrict__ binned,
                                                  PackArgs pa, u16* __restrict__ wpk) {
    __shared__ int sh[256];  // hist[128] | base_l[128]
    const int t = threadIdx.x;
    if ((int)blockIdx.x >= C) {
        pack_body(pa, wpk, blockIdx.x - C, t);
        return;
    }
    int* hist = sh;
    int* base_l = sh + 128;
    const int e0 = blockIdx.x * 4096;
    int sreg[16], dreg[16];
#pragma unroll
    for (int j = 0; j < 16; ++j) {
        int e = e0 + j * 256 + t;
        if (e < E) {
            sreg[j] = ei[e];
            dreg[j] = ei[E + e];
        } else {
            dreg[j] = -1;
        }
    }
    if (t < NB) hist[t] = 0;
    __syncthreads();
#pragma unroll
    for (int j = 0; j < 16; ++j)
        if (dreg[j] >= 0) atomicAdd(&hist[dreg[j] >> BSHIFT], 1);
    __syncthreads();
    if (t < NB) {
        base_l[t] = atomicAdd(&bin_cursor[t], hist[t]);
        hist[t] = 0;  // reuse as local fill
    }
    __syncthreads();
#pragma unroll
    for (int j = 0; j < 16; ++j)
        if (dreg[j] >= 0) {
            int b = dreg[j] >> BSHIFT;
            int pos = base_l[b] + atomicAdd(&hist[b], 1);
            if (pos < BCAP) binned[(size_t)b * BCAP + pos] = ((u32)(dreg[j] & (BSIZE - 1)) << 17) | (u32)sreg[j];
        }
}

// ---------------- MFMA GEMM tile body (forceinlined; used for encoder GEMM1 only) ----------------

template <int K, int M, int RT, int NSET, bool XBF16, bool OUT_BF16, bool BREL>
__device__ __forceinline__ void gemm_tile(const void* __restrict__ Xv, const u16* __restrict__ Bpk,
                                          const float* __restrict__ b0, const float* __restrict__ b1,
                                          const float* __restrict__ eps,
                                          void* __restrict__ Y0, float* __restrict__ Y1,
                                          u16* __restrict__ Z, int N, int col0, int row0, int t) {
    constexpr int CH = K / 32;
    constexpr int TPM = M >> 4;
    constexpr int SETSTRIDE = CH * TPM * 512;
    const int lane = t & 63, w = t >> 6;
    const int l15 = lane & 15, q = lane >> 4;

    s16x8 Bfr[NSET * CH * 4];
#pragma unroll
    for (int s = 0; s < NSET; ++s)
#pragma unroll
        for (int ch = 0; ch < CH; ++ch)
#pragma unroll
            for (int ct = 0; ct < 4; ++ct)
                Bfr[(s * CH + ch) * 4 + ct] =
                    *(const s16x8*)&Bpk[(size_t)s * SETSTRIDE + ((ch * TPM) + (col0 >> 4) + ct) * 512 + lane * 8];

    f32x4 acc[NSET][RT][4];
#pragma unroll
    for (int s = 0; s < NSET; ++s)
#pragma unroll
        for (int rt = 0; rt < RT; ++rt)
#pragma unroll
            for (int ct = 0; ct < 4; ++ct) acc[s][rt][ct] = 0.f;

#pragma unroll
    for (int ch = 0; ch < CH; ++ch) {
#pragma unroll
        for (int rt = 0; rt < RT; ++rt) {
            int r = row0 + (w * RT + rt) * 16 + l15;
            r = r < N ? r : N - 1;
            s16x8 ah, al;
            if (XBF16) {
                ah = *(const s16x8*)((const u16*)Xv + (size_t)r * K + (ch << 5) + (q << 3));
            } else {
                const float* xp = (const float*)Xv + (size_t)r * K + (ch << 5) + (q << 3);
                f32x4 x0 = *(const f32x4*)xp;
                f32x4 x1 = *(const f32x4*)(xp + 4);
                ah = pack_hi(x0, x1);
                al = pack_lo(x0, x1);
            }
#pragma unroll
            for (int s = 0; s < NSET; ++s)
#pragma unroll
                for (int ct = 0; ct < 4; ++ct) {
                    int fb = (s * CH + ch) * 4 + ct;
                    acc[s][rt][ct] = __builtin_amdgcn_mfma_f32_16x16x32_bf16(ah, Bfr[fb], acc[s][rt][ct], 0, 0, 0);
                    if (!XBF16)
                        acc[s][rt][ct] = __builtin_amdgcn_mfma_f32_16x16x32_bf16(al, Bfr[fb], acc[s][rt][ct], 0, 0, 0);
                }
        }
    }

#pragma unroll
    for (int rt = 0; rt < RT; ++rt)
#pragma unroll
        for (int ct = 0; ct < 4; ++ct)
#pragma unroll
            for (int reg = 0; reg < 4; ++reg) {
                int row = row0 + (w * RT + rt) * 16 + q * 4 + reg;
                if (row >= N) continue;
                int col = col0 + ct * 16 + l15;
                float v = acc[0][rt][ct][reg];
                if (BREL) v = fmaxf(v + b0[col], 0.f);
                if (OUT_BF16)
                    ((u16*)Y0)[(size_t)row * M + col] = f2bf(v);
                else
                    ((float*)Y0)[(size_t)row * M + col] = v;
            }
}

// ---------------- k2: full graph build (cnt+alloc+scatter, blocks [0,NB)) + WHOLE GEMM1 (blocks [NB,..)) ----
// Scatter now stores (src, dinv[dst]); the dinv[src] factor is applied inside the aggs
// (bit-exact: same f32 operands, same multiply). This removes the cross-bin dependency
// that forced the old k2/k3 split — cnt, alloc, and scatter are all bin-local.

__global__ __launch_bounds__(256, 3) void k_graph_gemm1(const u32* __restrict__ binned,
                                                        const int* __restrict__ bin_cursor, int N, int NB,
                                                        int* __restrict__ cnt, float* __restrict__ dinv,
                                                        int* __restrict__ row_start, int* __restrict__ cursor,
                                                        int2* __restrict__ edges,
                                                        const float* __restrict__ x, const u16* __restrict__ wpk,
                                                        u16* __restrict__ R1) {
    __shared__ int cnt_l[BSIZE];
    __shared__ int rs_l[BSIZE];
    __shared__ float dv_l[BSIZE];
    __shared__ int fill_l[BSIZE];
    __shared__ int wave_sum[5];
    __shared__ int base_s;
    const int t = threadIdx.x;
    const int b = blockIdx.x;
    if (b >= NB) {
        int idx = b - NB;
        gemm_tile<128, 128, 2, 1, false, true, false>(x, wpk, nullptr, nullptr, nullptr, R1, nullptr, nullptr,
                                                      N, (idx & 1) * 64, (idx >> 1) * 128, t);
        return;
    }
    const int lane = t & 63, w = t >> 6;
    cnt_l[t] = 0;
    cnt_l[t + 256] = 0;
    __syncthreads();
    const int n = min(bin_cursor[b], BCAP);
    for (int i = t; i < n; i += 256) atomicAdd(&cnt_l[binned[(size_t)b * BCAP + i] >> 17], 1);
    __syncthreads();
    int c0 = cnt_l[2 * t], c1 = cnt_l[2 * t + 1];
    int p0 = (c0 + 7) & ~7, p1 = (c1 + 7) & ~7;
    int s = p0 + p1;
    int incl = s;
#pragma unroll
    for (int o = 1; o < 64; o <<= 1) {
        int v = __shfl_up(incl, o, 64);
        if (lane >= o) incl += v;
    }
    if (lane == 63) wave_sum[w] = incl;
    __syncthreads();
    if (t == 0) {
        int acc = 0;
#pragma unroll
        for (int i = 0; i < 4; ++i) {
            int v = wave_sum[i];
            wave_sum[i] = acc;
            acc += v;
        }
        base_s = atomicAdd(cursor, acc);
    }
    __syncthreads();
    int excl = incl - s + wave_sum[w] + base_s;
    float d0 = rsqrtf((float)(c0 + 1)), d1 = rsqrtf((float)(c1 + 1));
    int v0 = b * BSIZE + 2 * t;
    if (v0 < N) {
        cnt[v0] = c0;
        dinv[v0] = d0;
        row_start[v0] = excl;
    }
    if (v0 + 1 < N) {
        cnt[v0 + 1] = c1;
        dinv[v0 + 1] = d1;
        row_start[v0 + 1] = excl + p0;
    }
    rs_l[2 * t] = excl;
    rs_l[2 * t + 1] = excl + p0;
    dv_l[2 * t] = d0;
    dv_l[2 * t + 1] = d1;
    fill_l[2 * t] = 0;
    fill_l[2 * t + 1] = 0;
    __syncthreads();
    for (int i = t; i < n; i += 256) {
        u32 e = binned[(size_t)b * BCAP + i];
        int dl = e >> 17;
        int src = e & 0x1FFFF;
        int pos = rs_l[dl] + atomicAdd(&fill_l[dl], 1);
        edges[pos] = make_int2(src, __float_as_int(dv_l[dl]));
    }
    __syncthreads();
#pragma unroll
    for (int hh = 0; hh < 2; ++hh) {
        int d = t + hh * 256;
        int v = b * BSIZE + d;
        if (v >= N) continue;
        int c = fill_l[d];
        int pc = (c + 7) & ~7;
        for (int j = c; j < pc; ++j) edges[rs_l[d] + j] = make_int2(0, 0);
    }
}

// ---------------- agg inner loops (FP order identical; wgt = e.y * dinv[src], bit-exact product) -----------

__device__ __forceinline__ void agg_row128(const u32* __restrict__ hp, const int2* __restrict__ edges,
                                           const float* __restrict__ dvg,
                                           int start, int pc, int lane, float& a0, float& a1) {
    if (!pc) return;
    int2 e[8];
#pragma unroll
    for (int j = 0; j < 8; ++j) e[j] = edges[start + j];
    for (int i = 0; i < pc; i += 8) {
        u32 h[8];
        float wv[8];
#pragma unroll
        for (int j = 0; j < 8; ++j) {
            h[j] = hp[(size_t)e[j].x * 64 + lane];
            wv[j] = __int_as_float(e[j].y) * dvg[e[j].x];
        }
        if (i + 8 < pc) {
#pragma unroll
            for (int j = 0; j < 8; ++j) e[j] = edges[start + i + 8 + j];
        }
#pragma unroll
        for (int j = 0; j < 8; ++j) {
            a0 = fmaf(wv[j], bf2f((u16)h[j]), a0);
            a1 = fmaf(wv[j], bf2f((u16)(h[j] >> 16)), a1);
        }
    }
}

__device__ __forceinline__ void agg_row64(const u16* __restrict__ hin, const int2* __restrict__ edges,
                                          const float* __restrict__ dvg,
                                          int start, int pc, int lane, float& a0) {
    if (!pc) return;
    int2 e[8];
#pragma unroll
    for (int j = 0; j < 8; ++j) e[j] = edges[start + j];
    for (int i = 0; i < pc; i += 8) {
        u16 h[8];
        float wv[8];
#pragma unroll
        for (int j = 0; j < 8; ++j) {
            h[j] = hin[(size_t)e[j].x * 64 + lane];
            wv[j] = __int_as_float(e[j].y) * dvg[e[j].x];
        }
        if (i + 8 < pc) {
#pragma unroll
            for (int j = 0; j < 8; ++j) e[j] = edges[start + i + 8 + j];
        }
#pragma unroll
        for (int j = 0; j < 8; ++j) a0 = fmaf(wv[j], bf2f(h[j]), a0);
    }
}

// ---------------- k3: agg1 (+be1+relu) fused with encoder GEMM2 via LDS+MFMA -> W1 (bf16 64ch) -------------

__global__ __launch_bounds__(256) void k_agg1_g2(const u16* __restrict__ R1, const int2* __restrict__ edges,
                                                 const int* __restrict__ row_start, const int* __restrict__ cnt,
                                                 const float* __restrict__ dinv, const float* __restrict__ be1,
                                                 const u16* __restrict__ Bpk, u16* __restrict__ W1, int N) {
    __shared__ u16 Ar[16 * 136];
    const int t = threadIdx.x, w = t >> 6, lane = t & 63;
    const u32* hp = (const u32*)R1;
#pragma unroll
    for (int i = 0; i < 4; ++i) {
        const int r = w * 4 + i;
        const int v = blockIdx.x * 16 + r;
        float a0 = 0.f, a1 = 0.f;
        if (v < N) {
            const int start = __builtin_amdgcn_readfirstlane(row_start[v]);
            const int c = __builtin_amdgcn_readfirstlane(cnt[v]);
            const int pc = (c + 7) & ~7;
            agg_row128(hp, edges, dinv, start, pc, lane, a0, a1);
            float dv = dinv[v], sw = dv * dv;
            u32 hs = hp[(size_t)v * 64 + lane];
            a0 = fmaf(sw, bf2f((u16)hs), a0);
            a1 = fmaf(sw, bf2f((u16)(hs >> 16)), a1);
            float2 bp = ((const float2*)be1)[lane];
            a0 += bp.x;
            a1 += bp.y;
            a0 = fmaxf(a0, 0.f);
            a1 = fmaxf(a1, 0.f);
        }
        ((u32*)Ar)[r * 68 + lane] = (u32)f2bf(a0) | ((u32)f2bf(a1) << 16);
    }
    __syncthreads();
    // GEMM2: K=128 (CH=4), M=64 (TPM=4), wave handles ct=w
    const int l15 = lane & 15, q = lane >> 4;
    f32x4 acc = 0.f;
#pragma unroll
    for (int ch = 0; ch < 4; ++ch) {
        s16x8 ah = *(const s16x8*)&Ar[l15 * 136 + ch * 32 + q * 8];
        s16x8 b = *(const s16x8*)&Bpk[(ch * 4 + w) * 512 + lane * 8];
        acc = __builtin_amdgcn_mfma_f32_16x16x32_bf16(ah, b, acc, 0, 0, 0);
    }
#pragma unroll
    for (int reg = 0; reg < 4; ++reg) {
        int row = blockIdx.x * 16 + q * 4 + reg;
        if (row >= N) continue;
        int col = w * 16 + l15;
        W1[(size_t)row * 64 + col] = f2bf(acc[reg]);
    }
}

// ---------------- k4: agg2 (+be2) fused with mu/logvar GEMM + reparameterize -> out_mu, out_lv, Zb ---------

__global__ __launch_bounds__(256) void k_agg2_mlv(const u16* __restrict__ W1, const int2* __restrict__ edges,
                                                  const int* __restrict__ row_start, const int* __restrict__ cnt,
                                                  const float* __restrict__ dinv, const float* __restrict__ be2,
                                                  const u16* __restrict__ Bmu, const u16* __restrict__ Blv,
                                                  const float* __restrict__ bmu, const float* __restrict__ blv,
                                                  const float* __restrict__ eps,
                                                  float* __restrict__ out_mu, float* __restrict__ out_lv,
                                                  u16* __restrict__ Zb, int N) {
    __shared__ float Af[16 * 68];
    const int t = threadIdx.x, w = t >> 6, lane = t & 63;
#pragma unroll
    for (int i = 0; i < 4; ++i) {
        const int r = w * 4 + i;
        const int v = blockIdx.x * 16 + r;
        float a0 = 0.f;
        if (v < N) {
            const int start = __builtin_amdgcn_readfirstlane(row_start[v]);
            const int c = __builtin_amdgcn_readfirstlane(cnt[v]);
            const int pc = (c + 7) & ~7;
            agg_row64(W1, edges, dinv, start, pc, lane, a0);
            float dv = dinv[v];
            a0 = fmaf(dv * dv, bf2f(W1[(size_t)v * 64 + lane]), a0);
            a0 += be2[lane];
        }
        Af[r * 68 + lane] = a0;
    }
    __syncthreads();
    // mu/lv GEMM: K=64 (CH=2), M=64 (TPM=4), wave ct=w, f32 A path (hi then lo)
    const int l15 = lane & 15, q = lane >> 4;
    f32x4 accm = 0.f, accl = 0.f;
#pragma unroll
    for (int ch = 0; ch < 2; ++ch) {
        f32x4 x0 = *(const f32x4*)&Af[l15 * 68 + ch * 32 + q * 8];
        f32x4 x1 = *(const f32x4*)&Af[l15 * 68 + ch * 32 + q * 8 + 4];
        s16x8 ah = pack_hi(x0, x1);
        s16x8 al = pack_lo(x0, x1);
        s16x8 bm = *(const s16x8*)&Bmu[(ch * 4 + w) * 512 + lane * 8];
        s16x8 bl = *(const s16x8*)&Blv[(ch * 4 + w) * 512 + lane * 8];
        accm = __builtin_amdgcn_mfma_f32_16x16x32_bf16(ah, bm, accm, 0, 0, 0);
        accm = __builtin_amdgcn_mfma_f32_16x16x32_bf16(al, bm, accm, 0, 0, 0);
        accl = __builtin_amdgcn_mfma_f32_16x16x32_bf16(ah, bl, accl, 0, 0, 0);
        accl = __builtin_amdgcn_mfma_f32_16x16x32_bf16(al, bl, accl, 0, 0, 0);
    }
#pragma unroll
    for (int reg = 0; reg < 4; ++reg) {
        int row = blockIdx.x * 16 + q * 4 + reg;
        if (row >= N) continue;
        int col = w * 16 + l15;
        size_t o = (size_t)row * 64 + col;
        float mu = accm[reg] + bmu[col];
        float lv = accl[reg] + blv[col];
        out_mu[o] = mu;
        out_lv[o] = lv;
        Zb[o] = f2bf(mu + eps[o] * expf(0.5f * lv));
    }
}

// ---------------- k5: agg3 (z) fused with decoder GEMM1 (+bd1+relu) AND GEMM2 -> R1 (bf16 128ch) -----------

__global__ __launch_bounds__(256) void k_agg3_d12(const u16* __restrict__ Zb, const int2* __restrict__ edges,
                                                  const int* __restrict__ row_start, const int* __restrict__ cnt,
                                                  const float* __restrict__ dinv,
                                                  const u16* __restrict__ Bd1, const u16* __restrict__ Bd2,
                                                  const float* __restrict__ bd1, u16* __restrict__ R1, int N) {
    __shared__ float Zr[16 * 68];
    __shared__ u16 Br[16 * 136];
    const int t = threadIdx.x, w = t >> 6, lane = t & 63;
#pragma unroll
    for (int i = 0; i < 4; ++i) {
        const int r = w * 4 + i;
        const int v = blockIdx.x * 16 + r;
        float a0 = 0.f;
        if (v < N) {
            const int start = __builtin_amdgcn_readfirstlane(row_start[v]);
            const int c = __builtin_amdgcn_readfirstlane(cnt[v]);
            const int pc = (c + 7) & ~7;
            agg_row64(Zb, edges, dinv, start, pc, lane, a0);
            float dv = dinv[v];
            a0 = fmaf(dv * dv, bf2f(Zb[(size_t)v * 64 + lane]), a0);
        }
        Zr[r * 68 + lane] = a0;
    }
    __syncthreads();
    const int l15 = lane & 15, q = lane >> 4;
    // d1: K=64 (CH=2), M=128 (TPM=8), wave cols ct in {w, w+4}, f32 A path
    {
        f32x4 acc1[2];
        acc1[0] = 0.f;
        acc1[1] = 0.f;
#pragma unroll
        for (int ch = 0; ch < 2; ++ch) {
            f32x4 x0 = *(const f32x4*)&Zr[l15 * 68 + ch * 32 + q * 8];
            f32x4 x1 = *(const f32x4*)&Zr[l15 * 68 + ch * 32 + q * 8 + 4];
            s16x8 ah = pack_hi(x0, x1);
            s16x8 al = pack_lo(x0, x1);
#pragma unroll
            for (int cti = 0; cti < 2; ++cti) {
                s16x8 b = *(const s16x8*)&Bd1[(ch * 8 + w + cti * 4) * 512 + lane * 8];
                acc1[cti] = __builtin_amdgcn_mfma_f32_16x16x32_bf16(ah, b, acc1[cti], 0, 0, 0);
                acc1[cti] = __builtin_amdgcn_mfma_f32_16x16x32_bf16(al, b, acc1[cti], 0, 0, 0);
            }
        }
#pragma unroll
        for (int cti = 0; cti < 2; ++cti)
#pragma unroll
            for (int reg = 0; reg < 4; ++reg) {
                int col = (w + cti * 4) * 16 + l15;
                float v = fmaxf(acc1[cti][reg] + bd1[col], 0.f);
                Br[(q * 4 + reg) * 136 + col] = f2bf(v);
            }
    }
    __syncthreads();
    // d2: K=128 (CH=4), M=128 (TPM=8), wave cols ct in {w, w+4}, bf16 A path
    {
        f32x4 acc2[2];
        acc2[0] = 0.f;
        acc2[1] = 0.f;
#pragma unroll
        for (int ch = 0; ch < 4; ++ch) {
            s16x8 ah = *(const s16x8*)&Br[l15 * 136 + ch * 32 + q * 8];
#pragma unroll
            for (int cti = 0; cti < 2; ++cti) {
                s16x8 b = *(const s16x8*)&Bd2[(ch * 8 + w + cti * 4) * 512 + lane * 8];
                acc2[cti] = __builtin_amdgcn_mfma_f32_16x16x32_bf16(ah, b, acc2[cti], 0, 0, 0);
            }
        }
#pragma unroll
        for (int cti = 0; cti < 2; ++cti)
#pragma unroll
            for (int reg = 0; reg < 4; ++reg) {
                int row = blockIdx.x * 16 + q * 4 + reg;
                if (row >= N) continue;
                int col = (w + cti * 4) * 16 + l15;
                R1[(size_t)row * 128 + col] = f2bf(acc2[cti][reg]);
            }
    }
}

// ---------------- k6: final agg + bd2 -> out_d (f32), XCC-pinned channel-sliced -----------------------------
// slice = XCC_ID & 3 (authoritative, m09). Per-XCD gather hot set = N*64B = 3.2MB < 4MiB L2.
// Coarse-chunk work-steal (1 atomic per 512 nodes) avoids r5's per-item serialization.
// Output stores non-temporal (no write-allocate eviction of the hot slice); edges/meta
// temporal. Per-channel FP order identical to the unsliced version.

__global__ __launch_bounds__(256) void k_agg4s(const u16* __restrict__ hin, const int2* __restrict__ edges,
                                               const int* __restrict__ row_start, const int* __restrict__ cnt,
                                               const float* __restrict__ dinv, const float* __restrict__ bias,
                                               float* __restrict__ out, int N, int* __restrict__ cur) {
    __shared__ int s_c;
    const int t = threadIdx.x;
    const int w = t >> 6, l = t & 63;
    const int sub = l >> 4, li = l & 15;
    int xcd;
    asm("s_getreg_b32 %0, hwreg(HW_REG_XCC_ID, 0, 32)" : "=s"(xcd));
    const int slice = xcd & 3;
    const int off = slice * 16 + li;  // u32 offset within 64-u32 row
    const u32* hp = (const u32*)hin;
    const int NCH = (N + 511) >> 9;  // chunks of 512 nodes
    for (;;) {
        if (t == 0) s_c = atomicAdd(cur + slice, 1);
        __syncthreads();
        const int c = s_c;
        __syncthreads();
        if (c >= NCH) break;
        for (int it = 0; it < 32; ++it) {
            const int v = c * 512 + it * 16 + w * 4 + sub;
            if (v >= N) continue;
            const int start = row_start[v];
            const int pc = (cnt[v] + 7) & ~7;
            float a0 = 0.f, a1 = 0.f;
            for (int i = 0; i < pc; i += 8) {
                int2 e[8];
#pragma unroll
                for (int j = 0; j < 8; ++j) e[j] = edges[start + i + j];
                u32 h[8];
                float wv[8];
#pragma unroll
                for (int j = 0; j < 8; ++j) {
                    h[j] = hp[(size_t)(u32)e[j].x * 64 + off];
                    wv[j] = __int_as_float(e[j].y) * dinv[e[j].x];
                }
#pragma unroll
                for (int j = 0; j < 8; ++j) {
                    a0 = fmaf(wv[j], bf2f((u16)h[j]), a0);
                    a1 = fmaf(wv[j], bf2f((u16)(h[j] >> 16)), a1);
                }
            }
            float dv = dinv[v], sw = dv * dv;
            u32 hs = hp[(size_t)v * 64 + off];
            a0 = fmaf(sw, bf2f((u16)hs), a0);
            a1 = fmaf(sw, bf2f((u16)(hs >> 16)), a1);
            float2 bp = ((const float2*)bias)[off];
            a0 += bp.x;
            a1 += bp.y;
            f32x2 o;
            o.x = a0;
            o.y = a1;
            __builtin_nontemporal_store(o, (f32x2*)out + (size_t)v * 64 + off);
        }
    }
}

// ---------------- launch ----------------

extern "C" void kernel_launch(void* const* d_in, const int* in_sizes, int n_in,
                              void* d_out, int out_size, void* d_ws, size_t ws_size,
                              hipStream_t stream) {
    const float* x = (const float*)d_in[0];
    const int* ei = (const int*)d_in[1];
    const float* eps = (const float*)d_in[2];
    const float* We1 = (const float*)d_in[3];
    const float* be1 = (const float*)d_in[4];
    const float* We2 = (const float*)d_in[5];
    const float* be2 = (const float*)d_in[6];
    const float* Wmu = (const float*)d_in[7];
    const float* bmu = (const float*)d_in[8];
    const float* Wlv = (const float*)d_in[9];
    const float* blv = (const float*)d_in[10];
    const float* Wd1 = (const float*)d_in[11];
    const float* bd1 = (const float*)d_in[12];
    const float* Wd2 = (const float*)d_in[13];
    const float* bd2 = (const float*)d_in[14];

    const int N = in_sizes[0] / 128;  // 50000
    const int E = in_sizes[1] / 2;    // 800000
    const int ECAP = E + 8 * N;
    const int NB = (N + BSIZE - 1) >> BSHIFT;  // 98
    const int C = (E + 4095) / 4096;           // 196 bin blocks

    // ws: bin_cursor(128) | cursor(1) | slice_cur(4)@160 | pad | dinv@256 | row_start | cnt
    //   | edges(ECAP int2) | R1(u16 N*128) | W1(region, aliases binned) | Zb | Wpk
    int* bin_cursor = (int*)d_ws;
    int* cursor = bin_cursor + 128;
    int* slice_cur = bin_cursor + 160;
    float* dinv = (float*)(bin_cursor + 256);
    int* row_start = (int*)(dinv + N);
    int* cnt = row_start + N;
    int2* edges = (int2*)(cnt + N);
    u16* R1 = (u16*)(edges + ECAP);
    u16* W1 = R1 + (size_t)N * 128;  // uses only N*64; region aliases binned (dead after k2)
    u16* Zb = W1 + (size_t)N * 128;  // uses only N*64
    u16* Wpk = Zb + (size_t)N * 128;
    u32* binned = (u32*)W1;

    float* out_d = (float*)d_out;
    float* out_mu = out_d + (size_t)N * 128;
    float* out_lv = out_mu + (size_t)N * 64;

    hipMemsetAsync(d_ws, 0, 1024, stream);  // bin_cursor + cursor + slice_cur

    PackArgs pa;
    pa.w[0] = We1; pa.w[1] = We2; pa.w[2] = Wmu; pa.w[3] = Wlv; pa.w[4] = Wd1; pa.w[5] = Wd2;

    const int RB128 = (N + 127) / 128;  // 391
    const int FB = (N + 15) / 16;       // 3125 fused agg blocks

    // k1: bin + weight pack
    k_bin_pack<<<dim3(C + 384), dim3(256), 0, stream>>>(ei, E, NB, C, bin_cursor, binned, pa, Wpk);
    // k2: full graph build (cnt+alloc+scatter)  ||  WHOLE encoder GEMM1
    k_graph_gemm1<<<dim3(NB + 2 * RB128), dim3(256), 0, stream>>>(binned, bin_cursor, N, NB, cnt, dinv,
                                                                  row_start, cursor, edges, x, Wpk, R1);
    // k3: agg1 + be1 + relu + GEMM2 -> W1 (bf16 64ch)
    k_agg1_g2<<<dim3(FB), dim3(256), 0, stream>>>(R1, edges, row_start, cnt, dinv, be1, Wpk + 16384, W1, N);
    // k4: agg2 + be2 + mu/lv GEMM + reparameterize -> out_mu, out_lv, Zb (z bf16)
    k_agg2_mlv<<<dim3(FB), dim3(256), 0, stream>>>(W1, edges, row_start, cnt, dinv, be2, Wpk + 24576,
                                                   Wpk + 28672, bmu, blv, eps, out_mu, out_lv, Zb, N);
    // k5: agg3(z) + d1(+bd1+relu) + d2 -> R1 (bf16 128ch)
    k_agg3_d12<<<dim3(FB), dim3(256), 0, stream>>>(Zb, edges, row_start, cnt, dinv, Wpk + 32768,
                                                   Wpk + 40960, bd1, R1, N);
    // k6: final agg + bd2 -> out_d (f32), XCC-pinned sliced
    k_agg4s<<<dim3(1024), dim3(256), 0, stream>>>(R1, edges, row_start, cnt, dinv, bd2, out_d, N, slice_cur);
}

// Round 10
// 298.387 us; speedup vs baseline: 1.3525x; 1.3525x over previous
//
#include <hip/hip_runtime.h>
#include <math.h>

typedef unsigned short u16;
typedef unsigned int u32;
typedef __attribute__((ext_vector_type(8))) short s16x8;
typedef __attribute__((ext_vector_type(4))) float f32x4;

__device__ __forceinline__ float bf2f(u16 u) { return __uint_as_float(((u32)u) << 16); }
__device__ __forceinline__ u16 f2bf(float f) {
    u32 u = __float_as_uint(f);
    return (u16)((u + 0x7fffu + ((u >> 16) & 1u)) >> 16);  // RNE
}

union U4 { u32 u[4]; s16x8 v; };

__device__ __forceinline__ s16x8 pack_hi(f32x4 x0, f32x4 x1) {
    U4 r;
    r.u[0] = (__float_as_uint(x0.y) & 0xFFFF0000u) | (__float_as_uint(x0.x) >> 16);
    r.u[1] = (__float_as_uint(x0.w) & 0xFFFF0000u) | (__float_as_uint(x0.z) >> 16);
    r.u[2] = (__float_as_uint(x1.y) & 0xFFFF0000u) | (__float_as_uint(x1.x) >> 16);
    r.u[3] = (__float_as_uint(x1.w) & 0xFFFF0000u) | (__float_as_uint(x1.z) >> 16);
    return r.v;
}
__device__ __forceinline__ s16x8 pack_lo(f32x4 x0, f32x4 x1) {
    float e0 = x0.x - __uint_as_float(__float_as_uint(x0.x) & 0xFFFF0000u);
    float e1 = x0.y - __uint_as_float(__float_as_uint(x0.y) & 0xFFFF0000u);
    float e2 = x0.z - __uint_as_float(__float_as_uint(x0.z) & 0xFFFF0000u);
    float e3 = x0.w - __uint_as_float(__float_as_uint(x0.w) & 0xFFFF0000u);
    float e4 = x1.x - __uint_as_float(__float_as_uint(x1.x) & 0xFFFF0000u);
    float e5 = x1.y - __uint_as_float(__float_as_uint(x1.y) & 0xFFFF0000u);
    float e6 = x1.z - __uint_as_float(__float_as_uint(x1.z) & 0xFFFF0000u);
    float e7 = x1.w - __uint_as_float(__float_as_uint(x1.w) & 0xFFFF0000u);
    U4 r;
    r.u[0] = (__float_as_uint(e1) & 0xFFFF0000u) | (__float_as_uint(e0) >> 16);
    r.u[1] = (__float_as_uint(e3) & 0xFFFF0000u) | (__float_as_uint(e2) >> 16);
    r.u[2] = (__float_as_uint(e5) & 0xFFFF0000u) | (__float_as_uint(e4) >> 16);
    r.u[3] = (__float_as_uint(e7) & 0xFFFF0000u) | (__float_as_uint(e6) >> 16);
    return r.v;
}

#define BSHIFT 9
#define BSIZE 512
#define BCAP 10240  // entries per bin region; mean 8192, sigma ~90

struct PackArgs { const float* w[6]; };

// ---------------- weight pre-pack into MFMA B-fragment order (bf16 RNE) ----------------

__device__ __forceinline__ void pack_body(const PackArgs& pa, u16* __restrict__ out, int g, int t) {
    const int Ks[6] = {128, 128, 64, 64, 64, 128};
    const int Ms[6] = {128, 64, 64, 64, 128, 128};
    const int Off[6] = {0, 16384, 24576, 28672, 32768, 40960};
    int s = g >> 6;
    int id = (g & 63) * 256 + t;
    int K = Ks[s], M = Ms[s];
    if (id >= K * M) return;
    int ms = (M == 128) ? 7 : 6;
    int k = id >> ms, c = id & (M - 1);
    int chunk = k >> 5, j = k & 7, lq = (k >> 3) & 3;
    int ct = c >> 4, ln = (c & 15) + (lq << 4);
    out[Off[s] + (chunk * (M >> 4) + ct) * 512 + ln * 8 + j] = f2bf(pa.w[s][id]);
}

// ---------------- k1: bin edges by dst>>9 (blocks [0,C)) + weight pack (blocks [C,C+384)) ----------------

__global__ __launch_bounds__(256) void k_bin_pack(const int* __restrict__ ei, int E, int NB, int C,
                                                  int* __restrict__ bin_cursor, u32* __restrict__ binned,
                                                  PackArgs pa, u16* __restrict__ wpk) {
    __shared__ int sh[256];  // hist[128] | base_l[128]
    const int t = threadIdx.x;
    if ((int)blockIdx.x >= C) {
        pack_body(pa, wpk, blockIdx.x - C, t);
        return;
    }
    int* hist = sh;
    int* base_l = sh + 128;
    const int e0 = blockIdx.x * 4096;
    int sreg[16], dreg[16];
#pragma unroll
    for (int j = 0; j < 16; ++j) {
        int e = e0 + j * 256 + t;
        if (e < E) {
            sreg[j] = ei[e];
            dreg[j] = ei[E + e];
        } else {
            dreg[j] = -1;
        }
    }
    if (t < NB) hist[t] = 0;
    __syncthreads();
#pragma unroll
    for (int j = 0; j < 16; ++j)
        if (dreg[j] >= 0) atomicAdd(&hist[dreg[j] >> BSHIFT], 1);
    __syncthreads();
    if (t < NB) {
        base_l[t] = atomicAdd(&bin_cursor[t], hist[t]);
        hist[t] = 0;  // reuse as local fill
    }
    __syncthreads();
#pragma unroll
    for (int j = 0; j < 16; ++j)
        if (dreg[j] >= 0) {
            int b = dreg[j] >> BSHIFT;
            int pos = base_l[b] + atomicAdd(&hist[b], 1);
            if (pos < BCAP) binned[(size_t)b * BCAP + pos] = ((u32)(dreg[j] & (BSIZE - 1)) << 17) | (u32)sreg[j];
        }
}

// ---------------- MFMA GEMM tile body (forceinlined; used for encoder GEMM1 only) ----------------

template <int K, int M, int RT, int NSET, bool XBF16, bool OUT_BF16, bool BREL>
__device__ __forceinline__ void gemm_tile(const void* __restrict__ Xv, const u16* __restrict__ Bpk,
                                          const float* __restrict__ b0, const float* __restrict__ b1,
                                          const float* __restrict__ eps,
                                          void* __restrict__ Y0, float* __restrict__ Y1,
                                          u16* __restrict__ Z, int N, int col0, int row0, int t) {
    constexpr int CH = K / 32;
    constexpr int TPM = M >> 4;
    constexpr int SETSTRIDE = CH * TPM * 512;
    const int lane = t & 63, w = t >> 6;
    const int l15 = lane & 15, q = lane >> 4;

    s16x8 Bfr[NSET * CH * 4];
#pragma unroll
    for (int s = 0; s < NSET; ++s)
#pragma unroll
        for (int ch = 0; ch < CH; ++ch)
#pragma unroll
            for (int ct = 0; ct < 4; ++ct)
                Bfr[(s * CH + ch) * 4 + ct] =
                    *(const s16x8*)&Bpk[(size_t)s * SETSTRIDE + ((ch * TPM) + (col0 >> 4) + ct) * 512 + lane * 8];

    f32x4 acc[NSET][RT][4];
#pragma unroll
    for (int s = 0; s < NSET; ++s)
#pragma unroll
        for (int rt = 0; rt < RT; ++rt)
#pragma unroll
            for (int ct = 0; ct < 4; ++ct) acc[s][rt][ct] = 0.f;

#pragma unroll
    for (int ch = 0; ch < CH; ++ch) {
#pragma unroll
        for (int rt = 0; rt < RT; ++rt) {
            int r = row0 + (w * RT + rt) * 16 + l15;
            r = r < N ? r : N - 1;
            s16x8 ah, al;
            if (XBF16) {
                ah = *(const s16x8*)((const u16*)Xv + (size_t)r * K + (ch << 5) + (q << 3));
            } else {
                const float* xp = (const float*)Xv + (size_t)r * K + (ch << 5) + (q << 3);
                f32x4 x0 = *(const f32x4*)xp;
                f32x4 x1 = *(const f32x4*)(xp + 4);
                ah = pack_hi(x0, x1);
                al = pack_lo(x0, x1);
            }
#pragma unroll
            for (int s = 0; s < NSET; ++s)
#pragma unroll
                for (int ct = 0; ct < 4; ++ct) {
                    int fb = (s * CH + ch) * 4 + ct;
                    acc[s][rt][ct] = __builtin_amdgcn_mfma_f32_16x16x32_bf16(ah, Bfr[fb], acc[s][rt][ct], 0, 0, 0);
                    if (!XBF16)
                        acc[s][rt][ct] = __builtin_amdgcn_mfma_f32_16x16x32_bf16(al, Bfr[fb], acc[s][rt][ct], 0, 0, 0);
                }
        }
    }

#pragma unroll
    for (int rt = 0; rt < RT; ++rt)
#pragma unroll
        for (int ct = 0; ct < 4; ++ct)
#pragma unroll
            for (int reg = 0; reg < 4; ++reg) {
                int row = row0 + (w * RT + rt) * 16 + q * 4 + reg;
                if (row >= N) continue;
                int col = col0 + ct * 16 + l15;
                float v = acc[0][rt][ct][reg];
                if (BREL) v = fmaxf(v + b0[col], 0.f);
                if (OUT_BF16)
                    ((u16*)Y0)[(size_t)row * M + col] = f2bf(v);
                else
                    ((float*)Y0)[(size_t)row * M + col] = v;
            }
}

// ---------------- k2: full graph build (cnt+alloc+scatter, blocks [0,NB)) + WHOLE GEMM1 (blocks [NB,..)) ----
// Scatter stores (src, dinv[dst]); dinv[src] applied inside aggs (bit-exact product).

__global__ __launch_bounds__(256, 3) void k_graph_gemm1(const u32* __restrict__ binned,
                                                        const int* __restrict__ bin_cursor, int N, int NB,
                                                        int* __restrict__ cnt, float* __restrict__ dinv,
                                                        int* __restrict__ row_start, int* __restrict__ cursor,
                                                        int2* __restrict__ edges,
                                                        const float* __restrict__ x, const u16* __restrict__ wpk,
                                                        u16* __restrict__ R1) {
    __shared__ int cnt_l[BSIZE];
    __shared__ int rs_l[BSIZE];
    __shared__ float dv_l[BSIZE];
    __shared__ int fill_l[BSIZE];
    __shared__ int wave_sum[5];
    __shared__ int base_s;
    const int t = threadIdx.x;
    const int b = blockIdx.x;
    if (b >= NB) {
        int idx = b - NB;
        gemm_tile<128, 128, 2, 1, false, true, false>(x, wpk, nullptr, nullptr, nullptr, R1, nullptr, nullptr,
                                                      N, (idx & 1) * 64, (idx >> 1) * 128, t);
        return;
    }
    const int lane = t & 63, w = t >> 6;
    cnt_l[t] = 0;
    cnt_l[t + 256] = 0;
    __syncthreads();
    const int n = min(bin_cursor[b], BCAP);
    for (int i = t; i < n; i += 256) atomicAdd(&cnt_l[binned[(size_t)b * BCAP + i] >> 17], 1);
    __syncthreads();
    int c0 = cnt_l[2 * t], c1 = cnt_l[2 * t + 1];
    int p0 = (c0 + 7) & ~7, p1 = (c1 + 7) & ~7;
    int s = p0 + p1;
    int incl = s;
#pragma unroll
    for (int o = 1; o < 64; o <<= 1) {
        int v = __shfl_up(incl, o, 64);
        if (lane >= o) incl += v;
    }
    if (lane == 63) wave_sum[w] = incl;
    __syncthreads();
    if (t == 0) {
        int acc = 0;
#pragma unroll
        for (int i = 0; i < 4; ++i) {
            int v = wave_sum[i];
            wave_sum[i] = acc;
            acc += v;
        }
        base_s = atomicAdd(cursor, acc);
    }
    __syncthreads();
    int excl = incl - s + wave_sum[w] + base_s;
    float d0 = rsqrtf((float)(c0 + 1)), d1 = rsqrtf((float)(c1 + 1));
    int v0 = b * BSIZE + 2 * t;
    if (v0 < N) {
        cnt[v0] = c0;
        dinv[v0] = d0;
        row_start[v0] = excl;
    }
    if (v0 + 1 < N) {
        cnt[v0 + 1] = c1;
        dinv[v0 + 1] = d1;
        row_start[v0 + 1] = excl + p0;
    }
    rs_l[2 * t] = excl;
    rs_l[2 * t + 1] = excl + p0;
    dv_l[2 * t] = d0;
    dv_l[2 * t + 1] = d1;
    fill_l[2 * t] = 0;
    fill_l[2 * t + 1] = 0;
    __syncthreads();
    for (int i = t; i < n; i += 256) {
        u32 e = binned[(size_t)b * BCAP + i];
        int dl = e >> 17;
        int src = e & 0x1FFFF;
        int pos = rs_l[dl] + atomicAdd(&fill_l[dl], 1);
        edges[pos] = make_int2(src, __float_as_int(dv_l[dl]));
    }
    __syncthreads();
#pragma unroll
    for (int hh = 0; hh < 2; ++hh) {
        int d = t + hh * 256;
        int v = b * BSIZE + d;
        if (v >= N) continue;
        int c = fill_l[d];
        int pc = (c + 7) & ~7;
        for (int j = c; j < pc; ++j) edges[rs_l[d] + j] = make_int2(0, 0);
    }
}

// ---------------- agg inner loops (FP order identical; wgt = e.y * dinv[src], bit-exact product) -----------

__device__ __forceinline__ void agg_row128(const u32* __restrict__ hp, const int2* __restrict__ edges,
                                           const float* __restrict__ dvg,
                                           int start, int pc, int lane, float& a0, float& a1) {
    if (!pc) return;
    int2 e[8];
#pragma unroll
    for (int j = 0; j < 8; ++j) e[j] = edges[start + j];
    for (int i = 0; i < pc; i += 8) {
        u32 h[8];
        float wv[8];
#pragma unroll
        for (int j = 0; j < 8; ++j) {
            h[j] = hp[(size_t)e[j].x * 64 + lane];
            wv[j] = __int_as_float(e[j].y) * dvg[e[j].x];
        }
        if (i + 8 < pc) {
#pragma unroll
            for (int j = 0; j < 8; ++j) e[j] = edges[start + i + 8 + j];
        }
#pragma unroll
        for (int j = 0; j < 8; ++j) {
            a0 = fmaf(wv[j], bf2f((u16)h[j]), a0);
            a1 = fmaf(wv[j], bf2f((u16)(h[j] >> 16)), a1);
        }
    }
}

__device__ __forceinline__ void agg_row64(const u16* __restrict__ hin, const int2* __restrict__ edges,
                                          const float* __restrict__ dvg,
                                          int start, int pc, int lane, float& a0) {
    if (!pc) return;
    int2 e[8];
#pragma unroll
    for (int j = 0; j < 8; ++j) e[j] = edges[start + j];
    for (int i = 0; i < pc; i += 8) {
        u16 h[8];
        float wv[8];
#pragma unroll
        for (int j = 0; j < 8; ++j) {
            h[j] = hin[(size_t)e[j].x * 64 + lane];
            wv[j] = __int_as_float(e[j].y) * dvg[e[j].x];
        }
        if (i + 8 < pc) {
#pragma unroll
            for (int j = 0; j < 8; ++j) e[j] = edges[start + i + 8 + j];
        }
#pragma unroll
        for (int j = 0; j < 8; ++j) a0 = fmaf(wv[j], bf2f(h[j]), a0);
    }
}

// ---------------- k3: agg1 (+be1+relu) fused with encoder GEMM2 via LDS+MFMA -> W1 (bf16 64ch) -------------

__global__ __launch_bounds__(256) void k_agg1_g2(const u16* __restrict__ R1, const int2* __restrict__ edges,
                                                 const int* __restrict__ row_start, const int* __restrict__ cnt,
                                                 const float* __restrict__ dinv, const float* __restrict__ be1,
                                                 const u16* __restrict__ Bpk, u16* __restrict__ W1, int N) {
    __shared__ u16 Ar[16 * 136];
    const int t = threadIdx.x, w = t >> 6, lane = t & 63;
    const u32* hp = (const u32*)R1;
#pragma unroll
    for (int i = 0; i < 4; ++i) {
        const int r = w * 4 + i;
        const int v = blockIdx.x * 16 + r;
        float a0 = 0.f, a1 = 0.f;
        if (v < N) {
            const int start = __builtin_amdgcn_readfirstlane(row_start[v]);
            const int c = __builtin_amdgcn_readfirstlane(cnt[v]);
            const int pc = (c + 7) & ~7;
            agg_row128(hp, edges, dinv, start, pc, lane, a0, a1);
            float dv = dinv[v], sw = dv * dv;
            u32 hs = hp[(size_t)v * 64 + lane];
            a0 = fmaf(sw, bf2f((u16)hs), a0);
            a1 = fmaf(sw, bf2f((u16)(hs >> 16)), a1);
            float2 bp = ((const float2*)be1)[lane];
            a0 += bp.x;
            a1 += bp.y;
            a0 = fmaxf(a0, 0.f);
            a1 = fmaxf(a1, 0.f);
        }
        ((u32*)Ar)[r * 68 + lane] = (u32)f2bf(a0) | ((u32)f2bf(a1) << 16);
    }
    __syncthreads();
    // GEMM2: K=128 (CH=4), M=64 (TPM=4), wave handles ct=w
    const int l15 = lane & 15, q = lane >> 4;
    f32x4 acc = 0.f;
#pragma unroll
    for (int ch = 0; ch < 4; ++ch) {
        s16x8 ah = *(const s16x8*)&Ar[l15 * 136 + ch * 32 + q * 8];
        s16x8 b = *(const s16x8*)&Bpk[(ch * 4 + w) * 512 + lane * 8];
        acc = __builtin_amdgcn_mfma_f32_16x16x32_bf16(ah, b, acc, 0, 0, 0);
    }
#pragma unroll
    for (int reg = 0; reg < 4; ++reg) {
        int row = blockIdx.x * 16 + q * 4 + reg;
        if (row >= N) continue;
        int col = w * 16 + l15;
        W1[(size_t)row * 64 + col] = f2bf(acc[reg]);
    }
}

// ---------------- k4: agg2 (+be2) fused with mu/logvar GEMM + reparameterize -> out_mu, out_lv, Zb ---------

__global__ __launch_bounds__(256) void k_agg2_mlv(const u16* __restrict__ W1, const int2* __restrict__ edges,
                                                  const int* __restrict__ row_start, const int* __restrict__ cnt,
                                                  const float* __restrict__ dinv, const float* __restrict__ be2,
                                                  const u16* __restrict__ Bmu, const u16* __restrict__ Blv,
                                                  const float* __restrict__ bmu, const float* __restrict__ blv,
                                                  const float* __restrict__ eps,
                                                  float* __restrict__ out_mu, float* __restrict__ out_lv,
                                                  u16* __restrict__ Zb, int N) {
    __shared__ float Af[16 * 68];
    const int t = threadIdx.x, w = t >> 6, lane = t & 63;
#pragma unroll
    for (int i = 0; i < 4; ++i) {
        const int r = w * 4 + i;
        const int v = blockIdx.x * 16 + r;
        float a0 = 0.f;
        if (v < N) {
            const int start = __builtin_amdgcn_readfirstlane(row_start[v]);
            const int c = __builtin_amdgcn_readfirstlane(cnt[v]);
            const int pc = (c + 7) & ~7;
            agg_row64(W1, edges, dinv, start, pc, lane, a0);
            float dv = dinv[v];
            a0 = fmaf(dv * dv, bf2f(W1[(size_t)v * 64 + lane]), a0);
            a0 += be2[lane];
        }
        Af[r * 68 + lane] = a0;
    }
    __syncthreads();
    // mu/lv GEMM: K=64 (CH=2), M=64 (TPM=4), wave ct=w, f32 A path (hi then lo)
    const int l15 = lane & 15, q = lane >> 4;
    f32x4 accm = 0.f, accl = 0.f;
#pragma unroll
    for (int ch = 0; ch < 2; ++ch) {
        f32x4 x0 = *(const f32x4*)&Af[l15 * 68 + ch * 32 + q * 8];
        f32x4 x1 = *(const f32x4*)&Af[l15 * 68 + ch * 32 + q * 8 + 4];
        s16x8 ah = pack_hi(x0, x1);
        s16x8 al = pack_lo(x0, x1);
        s16x8 bm = *(const s16x8*)&Bmu[(ch * 4 + w) * 512 + lane * 8];
        s16x8 bl = *(const s16x8*)&Blv[(ch * 4 + w) * 512 + lane * 8];
        accm = __builtin_amdgcn_mfma_f32_16x16x32_bf16(ah, bm, accm, 0, 0, 0);
        accm = __builtin_amdgcn_mfma_f32_16x16x32_bf16(al, bm, accm, 0, 0, 0);
        accl = __builtin_amdgcn_mfma_f32_16x16x32_bf16(ah, bl, accl, 0, 0, 0);
        accl = __builtin_amdgcn_mfma_f32_16x16x32_bf16(al, bl, accl, 0, 0, 0);
    }
#pragma unroll
    for (int reg = 0; reg < 4; ++reg) {
        int row = blockIdx.x * 16 + q * 4 + reg;
        if (row >= N) continue;
        int col = w * 16 + l15;
        size_t o = (size_t)row * 64 + col;
        float mu = accm[reg] + bmu[col];
        float lv = accl[reg] + blv[col];
        out_mu[o] = mu;
        out_lv[o] = lv;
        Zb[o] = f2bf(mu + eps[o] * expf(0.5f * lv));
    }
}

// ---------------- k5: agg3 (z) fused with decoder GEMM1 (+bd1+relu) AND GEMM2 -> R1 (bf16 128ch) -----------

__global__ __launch_bounds__(256) void k_agg3_d12(const u16* __restrict__ Zb, const int2* __restrict__ edges,
                                                  const int* __restrict__ row_start, const int* __restrict__ cnt,
                                                  const float* __restrict__ dinv,
                                                  const u16* __restrict__ Bd1, const u16* __restrict__ Bd2,
                                                  const float* __restrict__ bd1, u16* __restrict__ R1, int N) {
    __shared__ float Zr[16 * 68];
    __shared__ u16 Br[16 * 136];
    const int t = threadIdx.x, w = t >> 6, lane = t & 63;
#pragma unroll
    for (int i = 0; i < 4; ++i) {
        const int r = w * 4 + i;
        const int v = blockIdx.x * 16 + r;
        float a0 = 0.f;
        if (v < N) {
            const int start = __builtin_amdgcn_readfirstlane(row_start[v]);
            const int c = __builtin_amdgcn_readfirstlane(cnt[v]);
            const int pc = (c + 7) & ~7;
            agg_row64(Zb, edges, dinv, start, pc, lane, a0);
            float dv = dinv[v];
            a0 = fmaf(dv * dv, bf2f(Zb[(size_t)v * 64 + lane]), a0);
        }
        Zr[r * 68 + lane] = a0;
    }
    __syncthreads();
    const int l15 = lane & 15, q = lane >> 4;
    // d1: K=64 (CH=2), M=128 (TPM=8), wave cols ct in {w, w+4}, f32 A path
    {
        f32x4 acc1[2];
        acc1[0] = 0.f;
        acc1[1] = 0.f;
#pragma unroll
        for (int ch = 0; ch < 2; ++ch) {
            f32x4 x0 = *(const f32x4*)&Zr[l15 * 68 + ch * 32 + q * 8];
            f32x4 x1 = *(const f32x4*)&Zr[l15 * 68 + ch * 32 + q * 8 + 4];
            s16x8 ah = pack_hi(x0, x1);
            s16x8 al = pack_lo(x0, x1);
#pragma unroll
            for (int cti = 0; cti < 2; ++cti) {
                s16x8 b = *(const s16x8*)&Bd1[(ch * 8 + w + cti * 4) * 512 + lane * 8];
                acc1[cti] = __builtin_amdgcn_mfma_f32_16x16x32_bf16(ah, b, acc1[cti], 0, 0, 0);
                acc1[cti] = __builtin_amdgcn_mfma_f32_16x16x32_bf16(al, b, acc1[cti], 0, 0, 0);
            }
        }
#pragma unroll
        for (int cti = 0; cti < 2; ++cti)
#pragma unroll
            for (int reg = 0; reg < 4; ++reg) {
                int col = (w + cti * 4) * 16 + l15;
                float v = fmaxf(acc1[cti][reg] + bd1[col], 0.f);
                Br[(q * 4 + reg) * 136 + col] = f2bf(v);
            }
    }
    __syncthreads();
    // d2: K=128 (CH=4), M=128 (TPM=8), wave cols ct in {w, w+4}, bf16 A path
    {
        f32x4 acc2[2];
        acc2[0] = 0.f;
        acc2[1] = 0.f;
#pragma unroll
        for (int ch = 0; ch < 4; ++ch) {
            s16x8 ah = *(const s16x8*)&Br[l15 * 136 + ch * 32 + q * 8];
#pragma unroll
            for (int cti = 0; cti < 2; ++cti) {
                s16x8 b = *(const s16x8*)&Bd2[(ch * 8 + w + cti * 4) * 512 + lane * 8];
                acc2[cti] = __builtin_amdgcn_mfma_f32_16x16x32_bf16(ah, b, acc2[cti], 0, 0, 0);
            }
        }
#pragma unroll
        for (int cti = 0; cti < 2; ++cti)
#pragma unroll
            for (int reg = 0; reg < 4; ++reg) {
                int row = blockIdx.x * 16 + q * 4 + reg;
                if (row >= N) continue;
                int col = (w + cti * 4) * 16 + l15;
                R1[(size_t)row * 128 + col] = f2bf(acc2[cti][reg]);
            }
    }
}

// ---------------- k6: final agg + bd2 -> out_d (f32), unsliced (r8-proven structure) -----------------------
// Slicing permanently abandoned: r9 PMC showed agg FETCH is compulsory per-XCD replication
// (8 XCDs x table), not thrash; pinned slicing traded table replication for edge replication
// (117 vs 124 MB) while collapsing occupancy. One node per wave, 8-deep gather, plain stores.

__global__ __launch_bounds__(256) void k_agg4(const u16* __restrict__ hin, const int2* __restrict__ edges,
                                              const int* __restrict__ row_start, const int* __restrict__ cnt,
                                              const float* __restrict__ dinv, const float* __restrict__ bias,
                                              float* __restrict__ out, int N) {
    const int v = blockIdx.x * 4 + (threadIdx.x >> 6);
    const int lane = threadIdx.x & 63;
    if (v >= N) return;
    const int start = __builtin_amdgcn_readfirstlane(row_start[v]);
    const int c = __builtin_amdgcn_readfirstlane(cnt[v]);
    const int pc = (c + 7) & ~7;
    const u32* hp = (const u32*)hin;
    float a0 = 0.f, a1 = 0.f;
    agg_row128(hp, edges, dinv, start, pc, lane, a0, a1);
    float dv = dinv[v], sw = dv * dv;
    u32 hs = hp[(size_t)v * 64 + lane];
    a0 = fmaf(sw, bf2f((u16)hs), a0);
    a1 = fmaf(sw, bf2f((u16)(hs >> 16)), a1);
    float2 bp = ((const float2*)bias)[lane];
    a0 += bp.x;
    a1 += bp.y;
    ((float2*)out)[(size_t)v * 64 + lane] = make_float2(a0, a1);
}

// ---------------- launch ----------------

extern "C" void kernel_launch(void* const* d_in, const int* in_sizes, int n_in,
                              void* d_out, int out_size, void* d_ws, size_t ws_size,
                              hipStream_t stream) {
    const float* x = (const float*)d_in[0];
    const int* ei = (const int*)d_in[1];
    const float* eps = (const float*)d_in[2];
    const float* We1 = (const float*)d_in[3];
    const float* be1 = (const float*)d_in[4];
    const float* We2 = (const float*)d_in[5];
    const float* be2 = (const float*)d_in[6];
    const float* Wmu = (const float*)d_in[7];
    const float* bmu = (const float*)d_in[8];
    const float* Wlv = (const float*)d_in[9];
    const float* blv = (const float*)d_in[10];
    const float* Wd1 = (const float*)d_in[11];
    const float* bd1 = (const float*)d_in[12];
    const float* Wd2 = (const float*)d_in[13];
    const float* bd2 = (const float*)d_in[14];

    const int N = in_sizes[0] / 128;  // 50000
    const int E = in_sizes[1] / 2;    // 800000
    const int ECAP = E + 8 * N;
    const int NB = (N + BSIZE - 1) >> BSHIFT;  // 98
    const int C = (E + 4095) / 4096;           // 196 bin blocks

    // ws: bin_cursor(128) | cursor(1)+pad | dinv@256 | row_start | cnt
    //   | edges(ECAP int2) | R1(u16 N*128) | W1(region, aliases binned) | Zb | Wpk
    int* bin_cursor = (int*)d_ws;
    int* cursor = bin_cursor + 128;
    float* dinv = (float*)(bin_cursor + 256);
    int* row_start = (int*)(dinv + N);
    int* cnt = row_start + N;
    int2* edges = (int2*)(cnt + N);
    u16* R1 = (u16*)(edges + ECAP);
    u16* W1 = R1 + (size_t)N * 128;  // uses only N*64; region aliases binned (dead after k2)
    u16* Zb = W1 + (size_t)N * 128;  // uses only N*64
    u16* Wpk = Zb + (size_t)N * 128;
    u32* binned = (u32*)W1;

    float* out_d = (float*)d_out;
    float* out_mu = out_d + (size_t)N * 128;
    float* out_lv = out_mu + (size_t)N * 64;

    hipMemsetAsync(d_ws, 0, 1024, stream);  // bin_cursor + cursor

    PackArgs pa;
    pa.w[0] = We1; pa.w[1] = We2; pa.w[2] = Wmu; pa.w[3] = Wlv; pa.w[4] = Wd1; pa.w[5] = Wd2;

    const int RB128 = (N + 127) / 128;  // 391
    const int AB = (N + 3) / 4;         // 12500
    const int FB = (N + 15) / 16;       // 3125 fused agg blocks

    // k1: bin + weight pack
    k_bin_pack<<<dim3(C + 384), dim3(256), 0, stream>>>(ei, E, NB, C, bin_cursor, binned, pa, Wpk);
    // k2: full graph build (cnt+alloc+scatter)  ||  WHOLE encoder GEMM1
    k_graph_gemm1<<<dim3(NB + 2 * RB128), dim3(256), 0, stream>>>(binned, bin_cursor, N, NB, cnt, dinv,
                                                                  row_start, cursor, edges, x, Wpk, R1);
    // k3: agg1 + be1 + relu + GEMM2 -> W1 (bf16 64ch)
    k_agg1_g2<<<dim3(FB), dim3(256), 0, stream>>>(R1, edges, row_start, cnt, dinv, be1, Wpk + 16384, W1, N);
    // k4: agg2 + be2 + mu/lv GEMM + reparameterize -> out_mu, out_lv, Zb (z bf16)
    k_agg2_mlv<<<dim3(FB), dim3(256), 0, stream>>>(W1, edges, row_start, cnt, dinv, be2, Wpk + 24576,
                                                   Wpk + 28672, bmu, blv, eps, out_mu, out_lv, Zb, N);
    // k5: agg3(z) + d1(+bd1+relu) + d2 -> R1 (bf16 128ch)
    k_agg3_d12<<<dim3(FB), dim3(256), 0, stream>>>(Zb, edges, row_start, cnt, dinv, Wpk + 32768,
                                                   Wpk + 40960, bd1, R1, N);
    // k6: final agg + bd2 -> out_d (f32)
    k_agg4<<<dim3(AB), dim3(256), 0, stream>>>(R1, edges, row_start, cnt, dinv, bd2, out_d, N);
}